// Round 12
// baseline (1228.005 us; speedup 1.0000x reference)
//
#include <hip/hip_runtime.h>

#define S_LEN 2048
#define BATCH 64

__device__ __forceinline__ float exp2f_fast(float x){ return __builtin_amdgcn_exp2f(x); }
__device__ __forceinline__ float rcpf_fast(float x){ return __builtin_amdgcn_rcpf(x); }
__device__ __forceinline__ float sigmoid_f(float x){
    return rcpf_fast(1.f + exp2f_fast(x * -1.44269504089f));
}
__device__ __forceinline__ float tanh_f(float x){
    return fmaf(rcpf_fast(1.f + exp2f_fast(x * -2.88539008178f)), 2.f, -1.f);
}
__device__ __forceinline__ float readlane_f(float v, int lane){
    return __builtin_bit_cast(float, __builtin_amdgcn_readlane(__builtin_bit_cast(int, v), lane));
}
__device__ __forceinline__ void swap16(float& a, float& b){
    asm("v_permlane16_swap_b32 %0, %1" : "+v"(a), "+v"(b));
}
__device__ __forceinline__ void swap32(float& a, float& b){
    asm("v_permlane32_swap_b32 %0, %1" : "+v"(a), "+v"(b));
}

// K1 (round-12): round-10 base (PASSED, 974.6 total) with the We1 broadcast
// moved OFF the LDS path. Round-10's k1 was LDS-writeback-BW bound (8 waves
// x 8 ds_read_b128 broadcast = ~512cy/iter-round); round-11's reg ping-pong
// on LDS added v_mov copies and regressed. Here: weights read from GLOBAL
// via wave-uniform pointers (-> s_load through K$, zero LDS/VGPR writeback;
// round-7-proven path) with a manual 2-row ping-pong (o += 2, named wA/wB,
// NO copy loop) so next row's s_loads hide under current row's FMAs.
// FMA chain text/order byte-identical to rounds 7/9/10. x tile staging and
// e2/xg0 tails are byte-exact round-10 text (wlds removed: 43KB LDS).
__global__ __launch_bounds__(256) void k1_embed(
    const float* __restrict__ x, const float* __restrict__ We1, const float* __restrict__ be1,
    const float* __restrict__ We2, const float* __restrict__ be2,
    const float* __restrict__ Wih0, const float* __restrict__ bih0, const float* __restrict__ bhh0,
    float* __restrict__ emb, float* __restrict__ xg0)
{
    __shared__ float tile[256*36];     // x chunk (single buffer, reg-prefetch)
    __shared__ float w2lds[512];       // We2 (row-major copy)
    __shared__ float wihlds[1024];     // Wih0 (row-major copy)
    const int tid = threadIdx.x;
    const size_t row0 = (size_t)blockIdx.x * 256;
    const float* __restrict__ xbase = x + row0 * 768;

    float h1[32];
    #pragma unroll
    for (int o = 0; o < 32; ++o) h1[o] = be1[o];

    // stage tail weights once (coalesced; layouts match global row-major)
    if (tid < 128)
        *reinterpret_cast<float4*>(w2lds + 4*tid) =
            *reinterpret_cast<const float4*>(We2 + 4*tid);
    *reinterpret_cast<float4*>(wihlds + 4*tid) =
        *reinterpret_cast<const float4*>(Wih0 + 4*tid);

    float4 st[8];
    #pragma unroll
    for (int it = 0; it < 8; ++it) {
        const int L = it*256 + tid, rr = L >> 3, c4 = L & 7;
        st[it] = *reinterpret_cast<const float4*>(xbase + (size_t)rr*768 + 4*c4);
    }
    #pragma unroll
    for (int it = 0; it < 8; ++it) {
        const int L = it*256 + tid, rr = L >> 3, c4 = L & 7;
        *reinterpret_cast<float4*>(&tile[rr*36 + 4*c4]) = st[it];
    }
    __syncthreads();

    for (int c = 0; c < 24; ++c) {
        if (c < 23) {
            const int kc = (c+1)*32;
            #pragma unroll
            for (int it = 0; it < 8; ++it) {
                const int L = it*256 + tid, rr = L >> 3, c4 = L & 7;
                st[it] = *reinterpret_cast<const float4*>(xbase + (size_t)rr*768 + kc + 4*c4);
            }
        }
        float4 xv[8];
        #pragma unroll
        for (int q = 0; q < 8; ++q)
            xv[q] = *reinterpret_cast<const float4*>(&tile[tid*36 + 4*q]);
        const int kc0 = c*32;
        // 2-row ping-pong over wave-uniform GLOBAL weight rows (s_load/K$).
        // Row o+1's loads issue before row o's FMAs; no register copies.
        {
            float4 wA0, wA1, wA2, wA3, wA4, wA5, wA6, wA7;
            float4 wB0, wB1, wB2, wB3, wB4, wB5, wB6, wB7;
            const float* wr0 = We1 + kc0;             // row 0 of this chunk
            wA0 = *reinterpret_cast<const float4*>(wr0 + 0);
            wA1 = *reinterpret_cast<const float4*>(wr0 + 4);
            wA2 = *reinterpret_cast<const float4*>(wr0 + 8);
            wA3 = *reinterpret_cast<const float4*>(wr0 + 12);
            wA4 = *reinterpret_cast<const float4*>(wr0 + 16);
            wA5 = *reinterpret_cast<const float4*>(wr0 + 20);
            wA6 = *reinterpret_cast<const float4*>(wr0 + 24);
            wA7 = *reinterpret_cast<const float4*>(wr0 + 28);
            #pragma unroll 1
            for (int o = 0; o < 32; o += 2) {
                const float* wrB = We1 + (size_t)(o+1)*768 + kc0;
                wB0 = *reinterpret_cast<const float4*>(wrB + 0);
                wB1 = *reinterpret_cast<const float4*>(wrB + 4);
                wB2 = *reinterpret_cast<const float4*>(wrB + 8);
                wB3 = *reinterpret_cast<const float4*>(wrB + 12);
                wB4 = *reinterpret_cast<const float4*>(wrB + 16);
                wB5 = *reinterpret_cast<const float4*>(wrB + 20);
                wB6 = *reinterpret_cast<const float4*>(wrB + 24);
                wB7 = *reinterpret_cast<const float4*>(wrB + 28);
                {
                    float a0=0.f, a1=0.f, a2=0.f, a3=0.f;
                    a0 = fmaf(xv[0].x, wA0.x, a0); a1 = fmaf(xv[0].y, wA0.y, a1);
                    a2 = fmaf(xv[0].z, wA0.z, a2); a3 = fmaf(xv[0].w, wA0.w, a3);
                    a0 = fmaf(xv[1].x, wA1.x, a0); a1 = fmaf(xv[1].y, wA1.y, a1);
                    a2 = fmaf(xv[1].z, wA1.z, a2); a3 = fmaf(xv[1].w, wA1.w, a3);
                    a0 = fmaf(xv[2].x, wA2.x, a0); a1 = fmaf(xv[2].y, wA2.y, a1);
                    a2 = fmaf(xv[2].z, wA2.z, a2); a3 = fmaf(xv[2].w, wA2.w, a3);
                    a0 = fmaf(xv[3].x, wA3.x, a0); a1 = fmaf(xv[3].y, wA3.y, a1);
                    a2 = fmaf(xv[3].z, wA3.z, a2); a3 = fmaf(xv[3].w, wA3.w, a3);
                    a0 = fmaf(xv[4].x, wA4.x, a0); a1 = fmaf(xv[4].y, wA4.y, a1);
                    a2 = fmaf(xv[4].z, wA4.z, a2); a3 = fmaf(xv[4].w, wA4.w, a3);
                    a0 = fmaf(xv[5].x, wA5.x, a0); a1 = fmaf(xv[5].y, wA5.y, a1);
                    a2 = fmaf(xv[5].z, wA5.z, a2); a3 = fmaf(xv[5].w, wA5.w, a3);
                    a0 = fmaf(xv[6].x, wA6.x, a0); a1 = fmaf(xv[6].y, wA6.y, a1);
                    a2 = fmaf(xv[6].z, wA6.z, a2); a3 = fmaf(xv[6].w, wA6.w, a3);
                    a0 = fmaf(xv[7].x, wA7.x, a0); a1 = fmaf(xv[7].y, wA7.y, a1);
                    a2 = fmaf(xv[7].z, wA7.z, a2); a3 = fmaf(xv[7].w, wA7.w, a3);
                    h1[o] += (a0+a1)+(a2+a3);
                }
                if (o < 30) {
                    const float* wrA = We1 + (size_t)(o+2)*768 + kc0;
                    wA0 = *reinterpret_cast<const float4*>(wrA + 0);
                    wA1 = *reinterpret_cast<const float4*>(wrA + 4);
                    wA2 = *reinterpret_cast<const float4*>(wrA + 8);
                    wA3 = *reinterpret_cast<const float4*>(wrA + 12);
                    wA4 = *reinterpret_cast<const float4*>(wrA + 16);
                    wA5 = *reinterpret_cast<const float4*>(wrA + 20);
                    wA6 = *reinterpret_cast<const float4*>(wrA + 24);
                    wA7 = *reinterpret_cast<const float4*>(wrA + 28);
                }
                {
                    float a0=0.f, a1=0.f, a2=0.f, a3=0.f;
                    a0 = fmaf(xv[0].x, wB0.x, a0); a1 = fmaf(xv[0].y, wB0.y, a1);
                    a2 = fmaf(xv[0].z, wB0.z, a2); a3 = fmaf(xv[0].w, wB0.w, a3);
                    a0 = fmaf(xv[1].x, wB1.x, a0); a1 = fmaf(xv[1].y, wB1.y, a1);
                    a2 = fmaf(xv[1].z, wB1.z, a2); a3 = fmaf(xv[1].w, wB1.w, a3);
                    a0 = fmaf(xv[2].x, wB2.x, a0); a1 = fmaf(xv[2].y, wB2.y, a1);
                    a2 = fmaf(xv[2].z, wB2.z, a2); a3 = fmaf(xv[2].w, wB2.w, a3);
                    a0 = fmaf(xv[3].x, wB3.x, a0); a1 = fmaf(xv[3].y, wB3.y, a1);
                    a2 = fmaf(xv[3].z, wB3.z, a2); a3 = fmaf(xv[3].w, wB3.w, a3);
                    a0 = fmaf(xv[4].x, wB4.x, a0); a1 = fmaf(xv[4].y, wB4.y, a1);
                    a2 = fmaf(xv[4].z, wB4.z, a2); a3 = fmaf(xv[4].w, wB4.w, a3);
                    a0 = fmaf(xv[5].x, wB5.x, a0); a1 = fmaf(xv[5].y, wB5.y, a1);
                    a2 = fmaf(xv[5].z, wB5.z, a2); a3 = fmaf(xv[5].w, wB5.w, a3);
                    a0 = fmaf(xv[6].x, wB6.x, a0); a1 = fmaf(xv[6].y, wB6.y, a1);
                    a2 = fmaf(xv[6].z, wB6.z, a2); a3 = fmaf(xv[6].w, wB6.w, a3);
                    a0 = fmaf(xv[7].x, wB7.x, a0); a1 = fmaf(xv[7].y, wB7.y, a1);
                    a2 = fmaf(xv[7].z, wB7.z, a2); a3 = fmaf(xv[7].w, wB7.w, a3);
                    h1[o+1] += (a0+a1)+(a2+a3);
                }
            }
        }
        __syncthreads();
        if (c < 23) {
            #pragma unroll
            for (int it = 0; it < 8; ++it) {
                const int L = it*256 + tid, rr = L >> 3, c4 = L & 7;
                *reinterpret_cast<float4*>(&tile[rr*36 + 4*c4]) = st[it];
            }
        }
        __syncthreads();
    }

    #pragma unroll
    for (int o = 0; o < 32; ++o) h1[o] = fmaxf(h1[o], 0.f);

    const size_t row = row0 + tid;
    float e2[16];
    #pragma unroll 1
    for (int m = 0; m < 16; ++m) {
        float acc = be2[m];
        #pragma unroll
        for (int h4 = 0; h4 < 8; ++h4) {
            const float4 wv = *reinterpret_cast<const float4*>(w2lds + m*32 + 4*h4);
            acc = fmaf(wv.x, h1[4*h4+0], acc);
            acc = fmaf(wv.y, h1[4*h4+1], acc);
            acc = fmaf(wv.z, h1[4*h4+2], acc);
            acc = fmaf(wv.w, h1[4*h4+3], acc);
        }
        e2[m] = acc;
    }
    float4* embo = reinterpret_cast<float4*>(emb + row*16);
    #pragma unroll
    for (int m = 0; m < 4; ++m)
        embo[m] = make_float4(e2[4*m], e2[4*m+1], e2[4*m+2], e2[4*m+3]);

    float* xgo = xg0 + row*64;
    #pragma unroll 1
    for (int g = 0; g < 16; ++g) {
        float4 v;
        float* vp = &v.x;
        #pragma unroll
        for (int q = 0; q < 4; ++q) {
            const int rr = 4*g + q;
            float acc = bih0[rr] + bhh0[rr];
            #pragma unroll
            for (int m4 = 0; m4 < 4; ++m4) {
                const float4 wv = *reinterpret_cast<const float4*>(wihlds + rr*16 + 4*m4);
                acc = fmaf(wv.x, e2[4*m4+0], acc);
                acc = fmaf(wv.y, e2[4*m4+1], acc);
                acc = fmaf(wv.z, e2[4*m4+2], acc);
                acc = fmaf(wv.w, e2[4*m4+3], acc);
            }
            vp[q] = acc;
        }
        *reinterpret_cast<float4*>(xgo + 4*g) = v;
    }
}

// K2: sequential double-LSTM scan. One wave per batch element. NO LDS:
// gate exchange via permlane16/32_swap, h broadcast via v_readlane -> SGPRs.
// Lane r = gate row (i:0-15, f:16-31, g:32-47, o:48-63), column j = r&15.
// Layer1 lags layer0 by one step.
// [FROZEN: chaotic recurrence — byte-exact round-0/3/5..11 source only]
__global__ __launch_bounds__(64) void k2_scan(
    const float* __restrict__ xg0,
    const float* __restrict__ Whh0,
    const float* __restrict__ Wih1, const float* __restrict__ Whh1,
    const float* __restrict__ bih1, const float* __restrict__ bhh1,
    float* __restrict__ flow)
{
    const int r = threadIdx.x;
    const int j = r & 15;
    const int gr = r >> 4;
    const bool grOdd = (gr & 1) != 0;
    const bool grHi  = gr >= 2;
    const bool isg   = (gr == 2);
    const int b = blockIdx.x;
    const float* __restrict__ xgp = xg0 + (size_t)b * S_LEN * 64 + r;

    float wA[16], wI[16], wH[16];
    #pragma unroll
    for (int m = 0; m < 16; ++m) {
        wA[m] = Whh0[r*16+m];
        wI[m] = Wih1[r*16+m];
        wH[m] = Whh1[r*16+m];
    }
    const float biasB = bih1[r] + bhh1[r];
    const float kMul = isg ? -2.88539008178f : -1.44269504089f;
    const float kScl = isg ? 2.f : 1.f;
    const float kOff = isg ? -1.f : 0.f;

    float vAs[16], vBs[16];
    #pragma unroll
    for (int m = 0; m < 16; ++m) { vAs[m] = 0.f; vBs[m] = 0.f; }
    float cA = 0.f, cB = 0.f;

    float xq0 = xgp[0], xq1 = xgp[64], xq2 = xgp[128], xq3 = xgp[192];
    const float* pf = xgp + 256;                     // prefetch (4 steps ahead)
    float* stp = flow + (size_t)b * S_LEN * 16 + j;  // store ptr (lanes<16)

    // activation: sigmoid rows, tanh for g rows (constants pre-selected)
    auto act = [&](float a) -> float {
        return fmaf(rcpf_fast(1.f + exp2f_fast(a * kMul)), kScl, kOff);
    };
    // all-group gate exchange: from own z, produce i,f,g,o for column j
    auto exch = [&](float z, float& gi, float& gf, float& gg, float& go) {
        float za = z, zb = z;  swap16(za, zb);
        float v1 = grOdd ? za : zb;                  // group gr^1
        float ya = z, yb = z;  swap32(ya, yb);
        float v2 = grHi ? ya : yb;                   // group gr^2
        float wa = v2, wb = v2; swap16(wa, wb);
        float v3 = grOdd ? wa : wb;                  // group gr^3
        float A0 = grOdd ? v1 : z;
        float A1 = grOdd ? z  : v1;
        float B0 = grOdd ? v3 : v2;
        float B1 = grOdd ? v2 : v3;
        gi = grHi ? B0 : A0;
        gf = grHi ? B1 : A1;
        gg = grHi ? A0 : B0;
        go = grHi ? A1 : B1;
    };

    auto step = [&](float& xslot, bool doL1) {
        const float xgcur = xslot;
        xslot = *pf; pf += 64;                       // ring prefetch

        // L0 pre-activation (uses vAs = hA[t-1] in SGPRs)
        float a00 = xgcur, a01 = 0.f, a02 = 0.f, a03 = 0.f;
        #pragma unroll
        for (int m = 0; m < 16; m += 4) {
            a00 = fmaf(vAs[m+0], wA[m+0], a00);
            a01 = fmaf(vAs[m+1], wA[m+1], a01);
            a02 = fmaf(vAs[m+2], wA[m+2], a02);
            a03 = fmaf(vAs[m+3], wA[m+3], a03);
        }
        const float a0 = (a00+a01)+(a02+a03);
        // L1 pre-activation (step t-1): Wih1@hA[t-1] + Whh1@hB[t-2]
        float a10 = biasB, a11 = 0.f, a12 = 0.f, a13 = 0.f;
        #pragma unroll
        for (int m = 0; m < 16; m += 4) {
            a10 = fmaf(vAs[m+0], wI[m+0], a10);
            a11 = fmaf(vAs[m+1], wI[m+1], a11);
            a12 = fmaf(vAs[m+2], wI[m+2], a12);
            a13 = fmaf(vAs[m+3], wI[m+3], a13);
            a10 = fmaf(vBs[m+0], wH[m+0], a10);
            a11 = fmaf(vBs[m+1], wH[m+1], a11);
            a12 = fmaf(vBs[m+2], wH[m+2], a12);
            a13 = fmaf(vBs[m+3], wH[m+3], a13);
        }
        const float a1 = (a10+a11)+(a12+a13);

        // ---- layer-0 cell ----
        float z0 = act(a0);
        float i0, f0, g0, o0;
        exch(z0, i0, f0, g0, o0);
        cA = fmaf(f0, cA, i0*g0);
        const float hA = o0 * tanh_f(cA);
        #pragma unroll
        for (int m = 0; m < 16; ++m) vAs[m] = readlane_f(hA, m);

        // ---- layer-1 cell (lagged) ----
        if (doL1) {
            float z1 = act(a1);
            float i1, f1, g1, o1;
            exch(z1, i1, f1, g1, o1);
            cB = fmaf(f1, cB, i1*g1);
            const float hB = o1 * tanh_f(cB);
            if (r < 16) *stp = hB;
            stp += 16;
            #pragma unroll
            for (int m = 0; m < 16; ++m) vBs[m] = readlane_f(hB, m);
        }
    };

    step(xq0, false);
    step(xq1, true);
    step(xq2, true);
    step(xq3, true);
    for (int it = 1; it < 512; ++it) {
        step(xq0, true);
        step(xq1, true);
        step(xq2, true);
        step(xq3, true);
    }
    // final layer-1 step (tau = S-1)
    {
        float a10 = biasB, a11 = 0.f, a12 = 0.f, a13 = 0.f;
        #pragma unroll
        for (int m = 0; m < 16; m += 4) {
            a10 = fmaf(vAs[m+0], wI[m+0], a10);
            a11 = fmaf(vAs[m+1], wI[m+1], a11);
            a12 = fmaf(vAs[m+2], wI[m+2], a12);
            a13 = fmaf(vAs[m+3], wI[m+3], a13);
            a10 = fmaf(vBs[m+0], wH[m+0], a10);
            a11 = fmaf(vBs[m+1], wH[m+1], a11);
            a12 = fmaf(vBs[m+2], wH[m+2], a12);
            a13 = fmaf(vBs[m+3], wH[m+3], a13);
        }
        const float a1 = (a10+a11)+(a12+a13);
        float z1 = act(a1);
        float i1, f1, g1, o1;
        exch(z1, i1, f1, g1, o1);
        cB = fmaf(f1, cB, i1*g1);
        const float hB = o1 * tanh_f(cB);
        if (r < 16) *stp = hB;
    }
}

// K34 (fused k3+k4): 192 blocks = 64 b x 3 output tiles, 512 threads.
// [byte-exact round-7..11 version — passed at absmax 2.0]
__global__ __launch_bounds__(512) void k34_cons_head(
    const float* __restrict__ emb, const float* __restrict__ flow,
    const float* __restrict__ Wc1, const float* __restrict__ bc1,
    const float* __restrict__ Wc2, const float* __restrict__ bc2,
    const float* __restrict__ Wd1, const float* __restrict__ bd1,
    const float* __restrict__ Wd2, const float* __restrict__ bd2,
    float* __restrict__ out)
{
    __shared__ __align__(16) float parts_s[8][16];
    __shared__ __align__(16) float T[16];
    __shared__ __align__(16) float R[1536];
    const int b = blockIdx.x / 3;
    const int ot = blockIdx.x % 3;
    const int tid = threadIdx.x;
    const int half = tid >> 8;            // 0/1  (matches old blockIdx half)
    const int tid256 = tid & 255;

    float p[16];
    #pragma unroll
    for (int m = 0; m < 16; ++m) p[m] = 0.f;

    for (int k = 0; k < 4; ++k) {
        const int t = half*1024 + k*256 + tid256;
        const int c = (t < S_LEN-1) ? t : (S_LEN-2);
        const float* __restrict__ fp = flow + ((size_t)b*S_LEN + c)*16;
        float fa[16], fb[16];
        #pragma unroll
        for (int m = 0; m < 16; m += 4) {
            float4 v = *(const float4*)(fp + m);
            fa[m]=v.x; fa[m+1]=v.y; fa[m+2]=v.z; fa[m+3]=v.w;
            float4 w = *(const float4*)(fp + 16 + m);
            fb[m]=w.x; fb[m+1]=w.y; fb[m+2]=w.z; fb[m+3]=w.w;
        }
        float s = bc2[0];
        #pragma unroll
        for (int h = 0; h < 16; ++h) {
            float ch = bc1[h];
            #pragma unroll
            for (int k2 = 0; k2 < 16; ++k2) ch = fmaf(Wc1[h*32+k2], fa[k2], ch);
            #pragma unroll
            for (int k2 = 0; k2 < 16; ++k2) ch = fmaf(Wc1[h*32+16+k2], fb[k2], ch);
            s = fmaf(Wc2[h], fmaxf(ch, 0.f), s);
        }
        float cons = sigmoid_f(s);

        // inline curvature weight (exact k1b expressions)
        float cw;
        if (t == 0 || t == S_LEN-1) {
            cw = 1.f / 1e-8f;
        } else {
            const float* e = emb + ((size_t)b*S_LEN + t) * 16;
            float s1 = 0.f, s2 = 0.f;
            #pragma unroll
            for (int m = 0; m < 16; m += 4) {
                float4 pp = *(const float4*)(e - 16 + m);
                float4 cc = *(const float4*)(e + m);
                float4 nn = *(const float4*)(e + 16 + m);
                float d0 = cc.x-pp.x, d1 = cc.y-pp.y, d2 = cc.z-pp.z, d3 = cc.w-pp.w;
                s1 += d0*d0 + d1*d1 + d2*d2 + d3*d3;
                float e0 = nn.x-2.f*cc.x+pp.x, e1 = nn.y-2.f*cc.y+pp.y;
                float e2_ = nn.z-2.f*cc.z+pp.z, e3 = nn.w-2.f*cc.w+pp.w;
                s2 += e0*e0 + e1*e1 + e2_*e2_ + e3*e3;
            }
            float first = sqrtf(s1), second = sqrtf(s2);
            float curv = second / (first + 1e-8f);
            cw = 1.f / (curv + 1e-8f);
        }

        float w = cons * cw;
        const bool last = (t == S_LEN-1);
        #pragma unroll
        for (int m = 0; m < 16; ++m) p[m] = fmaf(w, last ? fb[m] : fa[m], p[m]);
    }
    #pragma unroll
    for (int d = 1; d < 64; d <<= 1) {
        #pragma unroll
        for (int m = 0; m < 16; ++m) p[m] += __shfl_xor(p[m], d, 64);
    }
    if ((tid & 63) == 0) {
        const int wv = tid >> 6;          // == half*4 + wave-in-half: old layout
        #pragma unroll
        for (int m = 0; m < 16; ++m) parts_s[wv][m] = p[m];
    }
    __syncthreads();

    // ---- T (temporal mean) ----
    if (tid < 16) {
        float s = 0.f;
        #pragma unroll
        for (int cch = 0; cch < 8; ++cch)
            s += parts_s[cch][tid];
        T[tid] = s * (1.f/2048.f);
    }
    __syncthreads();
    // ---- R = relu(Wd1@T + bd1) ----
    #pragma unroll
    for (int hh = 0; hh < 3; ++hh) {
        int h = hh*512 + tid;
        float s = bd1[h];
        #pragma unroll
        for (int m = 0; m < 16; ++m) s = fmaf(Wd1[h*16+m], T[m], s);
        R[h] = fmaxf(s, 0.f);
    }
    __syncthreads();
    // ---- out tile: wave-cooperative coalesced GEMV ----
    {
        const int wv = tid >> 6;          // 0..7
        const int lane = tid & 63;
        #pragma unroll 4
        for (int oo = 0; oo < 32; ++oo) {
            const int o = (ot<<8) + wv*32 + oo;
            const float* wr = Wd2 + (size_t)o*1536;
            float acc = 0.f;
            #pragma unroll
            for (int kk = 0; kk < 6; ++kk) {
                const int h = kk*256 + lane*4;
                float4 w = *(const float4*)(wr + h);
                float4 rr = *(const float4*)(&R[h]);
                acc += w.x*rr.x + w.y*rr.y + w.z*rr.z + w.w*rr.w;
            }
            #pragma unroll
            for (int d = 1; d < 64; d <<= 1) acc += __shfl_xor(acc, d, 64);
            if (lane == 0) out[(size_t)b*768 + o] = bd2[o] + acc;
        }
    }
}

extern "C" void kernel_launch(void* const* d_in, const int* in_sizes, int n_in,
                              void* d_out, int out_size, void* d_ws, size_t ws_size,
                              hipStream_t stream)
{
    const float* x    = (const float*)d_in[0];
    const float* We1  = (const float*)d_in[1];
    const float* be1  = (const float*)d_in[2];
    const float* We2  = (const float*)d_in[3];
    const float* be2  = (const float*)d_in[4];
    const float* Wih0 = (const float*)d_in[5];
    const float* Whh0 = (const float*)d_in[6];
    const float* bih0 = (const float*)d_in[7];
    const float* bhh0 = (const float*)d_in[8];
    const float* Wih1 = (const float*)d_in[9];
    const float* Whh1 = (const float*)d_in[10];
    const float* bih1 = (const float*)d_in[11];
    const float* bhh1 = (const float*)d_in[12];
    const float* Wc1  = (const float*)d_in[13];
    const float* bc1  = (const float*)d_in[14];
    const float* Wc2  = (const float*)d_in[15];
    const float* bc2  = (const float*)d_in[16];
    const float* Wd1  = (const float*)d_in[17];
    const float* bd1  = (const float*)d_in[18];
    const float* Wd2  = (const float*)d_in[19];
    const float* bd2  = (const float*)d_in[20];
    float* out = (float*)d_out;

    float* ws    = (float*)d_ws;
    float* emb   = ws;                       // 64*2048*16  = 2,097,152 f
    float* xg0   = emb + 2097152;            // 64*2048*64  = 8,388,608 f
    float* flow  = xg0 + 8388608;            // 64*2048*16  = 2,097,152 f

    k1_embed<<<dim3(512), dim3(256), 0, stream>>>(x, We1, be1, We2, be2,
                                                  Wih0, bih0, bhh0, emb, xg0);
    k2_scan<<<dim3(64), dim3(64), 0, stream>>>(xg0, Whh0, Wih1, Whh1, bih1, bhh1, flow);
    k34_cons_head<<<dim3(192), dim3(512), 0, stream>>>(emb, flow, Wc1, bc1, Wc2, bc2,
                                                       Wd1, bd1, Wd2, bd2, out);
}

// Round 13
// 965.361 us; speedup vs baseline: 1.2721x; 1.2721x over previous
//
#include <hip/hip_runtime.h>

#define S_LEN 2048
#define BATCH 64

__device__ __forceinline__ float exp2f_fast(float x){ return __builtin_amdgcn_exp2f(x); }
__device__ __forceinline__ float rcpf_fast(float x){ return __builtin_amdgcn_rcpf(x); }
__device__ __forceinline__ float sigmoid_f(float x){
    return rcpf_fast(1.f + exp2f_fast(x * -1.44269504089f));
}
__device__ __forceinline__ float tanh_f(float x){
    return fmaf(rcpf_fast(1.f + exp2f_fast(x * -2.88539008178f)), 2.f, -1.f);
}
__device__ __forceinline__ float readlane_f(float v, int lane){
    return __builtin_bit_cast(float, __builtin_amdgcn_readlane(__builtin_bit_cast(int, v), lane));
}
__device__ __forceinline__ void swap16(float& a, float& b){
    asm("v_permlane16_swap_b32 %0, %1" : "+v"(a), "+v"(b));
}
__device__ __forceinline__ void swap32(float& a, float& b){
    asm("v_permlane32_swap_b32 %0, %1" : "+v"(a), "+v"(b));
}

// K1 (round-13): BYTE-EXACT round-10 version (best passing config, 974.6
// total) with exactly ONE token changed: o-loop `#pragma unroll 1` ->
// `#pragma unroll 2`. Round-10's residual cost was per-iteration
// serialization (8 ds_read -> lgkmcnt(0) -> 32 FMA, wait exposed every o).
// unroll 2 lets the compiler place FMA(o) under reads(o+1) with DISTINCT
// registers — no v_mov copies (round-11's mistake), +32 VGPR only.
// FMA chain text/order unchanged (4/4 such k1 edits passed at absmax 2.0).
__global__ __launch_bounds__(256) void k1_embed(
    const float* __restrict__ x, const float* __restrict__ We1, const float* __restrict__ be1,
    const float* __restrict__ We2, const float* __restrict__ be2,
    const float* __restrict__ Wih0, const float* __restrict__ bih0, const float* __restrict__ bhh0,
    float* __restrict__ emb, float* __restrict__ xg0)
{
    __shared__ float tile[256*36];     // x chunk (single buffer, reg-prefetch)
    __shared__ float wlds[1024];       // We1 chunk: [o*32 + k]
    __shared__ float w2lds[512];       // We2 (row-major copy)
    __shared__ float wihlds[1024];     // Wih0 (row-major copy)
    const int tid = threadIdx.x;
    const size_t row0 = (size_t)blockIdx.x * 256;
    const float* __restrict__ xbase = x + row0 * 768;

    float h1[32];
    #pragma unroll
    for (int o = 0; o < 32; ++o) h1[o] = be1[o];

    // stage tail weights once (coalesced; layouts match global row-major)
    if (tid < 128)
        *reinterpret_cast<float4*>(w2lds + 4*tid) =
            *reinterpret_cast<const float4*>(We2 + 4*tid);
    *reinterpret_cast<float4*>(wihlds + 4*tid) =
        *reinterpret_cast<const float4*>(Wih0 + 4*tid);

    const int wo = tid >> 3, wq = tid & 7;     // We1-chunk staging map
    float4 st[8];
    #pragma unroll
    for (int it = 0; it < 8; ++it) {
        const int L = it*256 + tid, rr = L >> 3, c4 = L & 7;
        st[it] = *reinterpret_cast<const float4*>(xbase + (size_t)rr*768 + 4*c4);
    }
    float4 wst = *reinterpret_cast<const float4*>(We1 + (size_t)wo*768 + 4*wq);
    #pragma unroll
    for (int it = 0; it < 8; ++it) {
        const int L = it*256 + tid, rr = L >> 3, c4 = L & 7;
        *reinterpret_cast<float4*>(&tile[rr*36 + 4*c4]) = st[it];
    }
    *reinterpret_cast<float4*>(&wlds[wo*32 + 4*wq]) = wst;
    __syncthreads();

    for (int c = 0; c < 24; ++c) {
        if (c < 23) {
            const int kc = (c+1)*32;
            #pragma unroll
            for (int it = 0; it < 8; ++it) {
                const int L = it*256 + tid, rr = L >> 3, c4 = L & 7;
                st[it] = *reinterpret_cast<const float4*>(xbase + (size_t)rr*768 + kc + 4*c4);
            }
            wst = *reinterpret_cast<const float4*>(We1 + (size_t)wo*768 + kc + 4*wq);
        }
        float4 xv[8];
        #pragma unroll
        for (int q = 0; q < 8; ++q)
            xv[q] = *reinterpret_cast<const float4*>(&tile[tid*36 + 4*q]);
        #pragma unroll 2
        for (int o = 0; o < 32; ++o) {
            const float* wrow = wlds + o*32;              // LDS broadcast reads
            float a0=0.f, a1=0.f, a2=0.f, a3=0.f;
            #pragma unroll
            for (int q = 0; q < 8; ++q) {
                float4 wv = *reinterpret_cast<const float4*>(wrow + 4*q);
                a0 = fmaf(xv[q].x, wv.x, a0);
                a1 = fmaf(xv[q].y, wv.y, a1);
                a2 = fmaf(xv[q].z, wv.z, a2);
                a3 = fmaf(xv[q].w, wv.w, a3);
            }
            h1[o] += (a0+a1)+(a2+a3);
        }
        __syncthreads();
        if (c < 23) {
            #pragma unroll
            for (int it = 0; it < 8; ++it) {
                const int L = it*256 + tid, rr = L >> 3, c4 = L & 7;
                *reinterpret_cast<float4*>(&tile[rr*36 + 4*c4]) = st[it];
            }
            *reinterpret_cast<float4*>(&wlds[wo*32 + 4*wq]) = wst;
        }
        __syncthreads();
    }

    #pragma unroll
    for (int o = 0; o < 32; ++o) h1[o] = fmaxf(h1[o], 0.f);

    const size_t row = row0 + tid;
    float e2[16];
    #pragma unroll 1
    for (int m = 0; m < 16; ++m) {
        float acc = be2[m];
        #pragma unroll
        for (int h = 0; h < 32; ++h) acc = fmaf(w2lds[m*32+h], h1[h], acc);
        e2[m] = acc;
    }
    float4* embo = reinterpret_cast<float4*>(emb + row*16);
    #pragma unroll
    for (int m = 0; m < 4; ++m)
        embo[m] = make_float4(e2[4*m], e2[4*m+1], e2[4*m+2], e2[4*m+3]);

    float* xgo = xg0 + row*64;
    #pragma unroll 1
    for (int g = 0; g < 16; ++g) {
        float4 v;
        float* vp = &v.x;
        #pragma unroll
        for (int q = 0; q < 4; ++q) {
            const int rr = 4*g + q;
            float acc = bih0[rr] + bhh0[rr];
            #pragma unroll
            for (int m = 0; m < 16; ++m) acc = fmaf(wihlds[rr*16+m], e2[m], acc);
            vp[q] = acc;
        }
        *reinterpret_cast<float4*>(xgo + 4*g) = v;
    }
}

// K2: sequential double-LSTM scan. One wave per batch element. NO LDS:
// gate exchange via permlane16/32_swap, h broadcast via v_readlane -> SGPRs.
// Lane r = gate row (i:0-15, f:16-31, g:32-47, o:48-63), column j = r&15.
// Layer1 lags layer0 by one step.
// [FROZEN: chaotic recurrence — byte-exact round-0/3/5..12 source only]
__global__ __launch_bounds__(64) void k2_scan(
    const float* __restrict__ xg0,
    const float* __restrict__ Whh0,
    const float* __restrict__ Wih1, const float* __restrict__ Whh1,
    const float* __restrict__ bih1, const float* __restrict__ bhh1,
    float* __restrict__ flow)
{
    const int r = threadIdx.x;
    const int j = r & 15;
    const int gr = r >> 4;
    const bool grOdd = (gr & 1) != 0;
    const bool grHi  = gr >= 2;
    const bool isg   = (gr == 2);
    const int b = blockIdx.x;
    const float* __restrict__ xgp = xg0 + (size_t)b * S_LEN * 64 + r;

    float wA[16], wI[16], wH[16];
    #pragma unroll
    for (int m = 0; m < 16; ++m) {
        wA[m] = Whh0[r*16+m];
        wI[m] = Wih1[r*16+m];
        wH[m] = Whh1[r*16+m];
    }
    const float biasB = bih1[r] + bhh1[r];
    const float kMul = isg ? -2.88539008178f : -1.44269504089f;
    const float kScl = isg ? 2.f : 1.f;
    const float kOff = isg ? -1.f : 0.f;

    float vAs[16], vBs[16];
    #pragma unroll
    for (int m = 0; m < 16; ++m) { vAs[m] = 0.f; vBs[m] = 0.f; }
    float cA = 0.f, cB = 0.f;

    float xq0 = xgp[0], xq1 = xgp[64], xq2 = xgp[128], xq3 = xgp[192];
    const float* pf = xgp + 256;                     // prefetch (4 steps ahead)
    float* stp = flow + (size_t)b * S_LEN * 16 + j;  // store ptr (lanes<16)

    // activation: sigmoid rows, tanh for g rows (constants pre-selected)
    auto act = [&](float a) -> float {
        return fmaf(rcpf_fast(1.f + exp2f_fast(a * kMul)), kScl, kOff);
    };
    // all-group gate exchange: from own z, produce i,f,g,o for column j
    auto exch = [&](float z, float& gi, float& gf, float& gg, float& go) {
        float za = z, zb = z;  swap16(za, zb);
        float v1 = grOdd ? za : zb;                  // group gr^1
        float ya = z, yb = z;  swap32(ya, yb);
        float v2 = grHi ? ya : yb;                   // group gr^2
        float wa = v2, wb = v2; swap16(wa, wb);
        float v3 = grOdd ? wa : wb;                  // group gr^3
        float A0 = grOdd ? v1 : z;
        float A1 = grOdd ? z  : v1;
        float B0 = grOdd ? v3 : v2;
        float B1 = grOdd ? v2 : v3;
        gi = grHi ? B0 : A0;
        gf = grHi ? B1 : A1;
        gg = grHi ? A0 : B0;
        go = grHi ? A1 : B1;
    };

    auto step = [&](float& xslot, bool doL1) {
        const float xgcur = xslot;
        xslot = *pf; pf += 64;                       // ring prefetch

        // L0 pre-activation (uses vAs = hA[t-1] in SGPRs)
        float a00 = xgcur, a01 = 0.f, a02 = 0.f, a03 = 0.f;
        #pragma unroll
        for (int m = 0; m < 16; m += 4) {
            a00 = fmaf(vAs[m+0], wA[m+0], a00);
            a01 = fmaf(vAs[m+1], wA[m+1], a01);
            a02 = fmaf(vAs[m+2], wA[m+2], a02);
            a03 = fmaf(vAs[m+3], wA[m+3], a03);
        }
        const float a0 = (a00+a01)+(a02+a03);
        // L1 pre-activation (step t-1): Wih1@hA[t-1] + Whh1@hB[t-2]
        float a10 = biasB, a11 = 0.f, a12 = 0.f, a13 = 0.f;
        #pragma unroll
        for (int m = 0; m < 16; m += 4) {
            a10 = fmaf(vAs[m+0], wI[m+0], a10);
            a11 = fmaf(vAs[m+1], wI[m+1], a11);
            a12 = fmaf(vAs[m+2], wI[m+2], a12);
            a13 = fmaf(vAs[m+3], wI[m+3], a13);
            a10 = fmaf(vBs[m+0], wH[m+0], a10);
            a11 = fmaf(vBs[m+1], wH[m+1], a11);
            a12 = fmaf(vBs[m+2], wH[m+2], a12);
            a13 = fmaf(vBs[m+3], wH[m+3], a13);
        }
        const float a1 = (a10+a11)+(a12+a13);

        // ---- layer-0 cell ----
        float z0 = act(a0);
        float i0, f0, g0, o0;
        exch(z0, i0, f0, g0, o0);
        cA = fmaf(f0, cA, i0*g0);
        const float hA = o0 * tanh_f(cA);
        #pragma unroll
        for (int m = 0; m < 16; ++m) vAs[m] = readlane_f(hA, m);

        // ---- layer-1 cell (lagged) ----
        if (doL1) {
            float z1 = act(a1);
            float i1, f1, g1, o1;
            exch(z1, i1, f1, g1, o1);
            cB = fmaf(f1, cB, i1*g1);
            const float hB = o1 * tanh_f(cB);
            if (r < 16) *stp = hB;
            stp += 16;
            #pragma unroll
            for (int m = 0; m < 16; ++m) vBs[m] = readlane_f(hB, m);
        }
    };

    step(xq0, false);
    step(xq1, true);
    step(xq2, true);
    step(xq3, true);
    for (int it = 1; it < 512; ++it) {
        step(xq0, true);
        step(xq1, true);
        step(xq2, true);
        step(xq3, true);
    }
    // final layer-1 step (tau = S-1)
    {
        float a10 = biasB, a11 = 0.f, a12 = 0.f, a13 = 0.f;
        #pragma unroll
        for (int m = 0; m < 16; m += 4) {
            a10 = fmaf(vAs[m+0], wI[m+0], a10);
            a11 = fmaf(vAs[m+1], wI[m+1], a11);
            a12 = fmaf(vAs[m+2], wI[m+2], a12);
            a13 = fmaf(vAs[m+3], wI[m+3], a13);
            a10 = fmaf(vBs[m+0], wH[m+0], a10);
            a11 = fmaf(vBs[m+1], wH[m+1], a11);
            a12 = fmaf(vBs[m+2], wH[m+2], a12);
            a13 = fmaf(vBs[m+3], wH[m+3], a13);
        }
        const float a1 = (a10+a11)+(a12+a13);
        float z1 = act(a1);
        float i1, f1, g1, o1;
        exch(z1, i1, f1, g1, o1);
        cB = fmaf(f1, cB, i1*g1);
        const float hB = o1 * tanh_f(cB);
        if (r < 16) *stp = hB;
    }
}

// K34 (fused k3+k4): 192 blocks = 64 b x 3 output tiles, 512 threads.
// [byte-exact round-7..12 version — passed at absmax 2.0]
__global__ __launch_bounds__(512) void k34_cons_head(
    const float* __restrict__ emb, const float* __restrict__ flow,
    const float* __restrict__ Wc1, const float* __restrict__ bc1,
    const float* __restrict__ Wc2, const float* __restrict__ bc2,
    const float* __restrict__ Wd1, const float* __restrict__ bd1,
    const float* __restrict__ Wd2, const float* __restrict__ bd2,
    float* __restrict__ out)
{
    __shared__ __align__(16) float parts_s[8][16];
    __shared__ __align__(16) float T[16];
    __shared__ __align__(16) float R[1536];
    const int b = blockIdx.x / 3;
    const int ot = blockIdx.x % 3;
    const int tid = threadIdx.x;
    const int half = tid >> 8;            // 0/1  (matches old blockIdx half)
    const int tid256 = tid & 255;

    float p[16];
    #pragma unroll
    for (int m = 0; m < 16; ++m) p[m] = 0.f;

    for (int k = 0; k < 4; ++k) {
        const int t = half*1024 + k*256 + tid256;
        const int c = (t < S_LEN-1) ? t : (S_LEN-2);
        const float* __restrict__ fp = flow + ((size_t)b*S_LEN + c)*16;
        float fa[16], fb[16];
        #pragma unroll
        for (int m = 0; m < 16; m += 4) {
            float4 v = *(const float4*)(fp + m);
            fa[m]=v.x; fa[m+1]=v.y; fa[m+2]=v.z; fa[m+3]=v.w;
            float4 w = *(const float4*)(fp + 16 + m);
            fb[m]=w.x; fb[m+1]=w.y; fb[m+2]=w.z; fb[m+3]=w.w;
        }
        float s = bc2[0];
        #pragma unroll
        for (int h = 0; h < 16; ++h) {
            float ch = bc1[h];
            #pragma unroll
            for (int k2 = 0; k2 < 16; ++k2) ch = fmaf(Wc1[h*32+k2], fa[k2], ch);
            #pragma unroll
            for (int k2 = 0; k2 < 16; ++k2) ch = fmaf(Wc1[h*32+16+k2], fb[k2], ch);
            s = fmaf(Wc2[h], fmaxf(ch, 0.f), s);
        }
        float cons = sigmoid_f(s);

        // inline curvature weight (exact k1b expressions)
        float cw;
        if (t == 0 || t == S_LEN-1) {
            cw = 1.f / 1e-8f;
        } else {
            const float* e = emb + ((size_t)b*S_LEN + t) * 16;
            float s1 = 0.f, s2 = 0.f;
            #pragma unroll
            for (int m = 0; m < 16; m += 4) {
                float4 pp = *(const float4*)(e - 16 + m);
                float4 cc = *(const float4*)(e + m);
                float4 nn = *(const float4*)(e + 16 + m);
                float d0 = cc.x-pp.x, d1 = cc.y-pp.y, d2 = cc.z-pp.z, d3 = cc.w-pp.w;
                s1 += d0*d0 + d1*d1 + d2*d2 + d3*d3;
                float e0 = nn.x-2.f*cc.x+pp.x, e1 = nn.y-2.f*cc.y+pp.y;
                float e2_ = nn.z-2.f*cc.z+pp.z, e3 = nn.w-2.f*cc.w+pp.w;
                s2 += e0*e0 + e1*e1 + e2_*e2_ + e3*e3;
            }
            float first = sqrtf(s1), second = sqrtf(s2);
            float curv = second / (first + 1e-8f);
            cw = 1.f / (curv + 1e-8f);
        }

        float w = cons * cw;
        const bool last = (t == S_LEN-1);
        #pragma unroll
        for (int m = 0; m < 16; ++m) p[m] = fmaf(w, last ? fb[m] : fa[m], p[m]);
    }
    #pragma unroll
    for (int d = 1; d < 64; d <<= 1) {
        #pragma unroll
        for (int m = 0; m < 16; ++m) p[m] += __shfl_xor(p[m], d, 64);
    }
    if ((tid & 63) == 0) {
        const int wv = tid >> 6;          // == half*4 + wave-in-half: old layout
        #pragma unroll
        for (int m = 0; m < 16; ++m) parts_s[wv][m] = p[m];
    }
    __syncthreads();

    // ---- T (temporal mean) ----
    if (tid < 16) {
        float s = 0.f;
        #pragma unroll
        for (int cch = 0; cch < 8; ++cch)
            s += parts_s[cch][tid];
        T[tid] = s * (1.f/2048.f);
    }
    __syncthreads();
    // ---- R = relu(Wd1@T + bd1) ----
    #pragma unroll
    for (int hh = 0; hh < 3; ++hh) {
        int h = hh*512 + tid;
        float s = bd1[h];
        #pragma unroll
        for (int m = 0; m < 16; ++m) s = fmaf(Wd1[h*16+m], T[m], s);
        R[h] = fmaxf(s, 0.f);
    }
    __syncthreads();
    // ---- out tile: wave-cooperative coalesced GEMV ----
    {
        const int wv = tid >> 6;          // 0..7
        const int lane = tid & 63;
        #pragma unroll 4
        for (int oo = 0; oo < 32; ++oo) {
            const int o = (ot<<8) + wv*32 + oo;
            const float* wr = Wd2 + (size_t)o*1536;
            float acc = 0.f;
            #pragma unroll
            for (int kk = 0; kk < 6; ++kk) {
                const int h = kk*256 + lane*4;
                float4 w = *(const float4*)(wr + h);
                float4 rr = *(const float4*)(&R[h]);
                acc += w.x*rr.x + w.y*rr.y + w.z*rr.z + w.w*rr.w;
            }
            #pragma unroll
            for (int d = 1; d < 64; d <<= 1) acc += __shfl_xor(acc, d, 64);
            if (lane == 0) out[(size_t)b*768 + o] = bd2[o] + acc;
        }
    }
}

extern "C" void kernel_launch(void* const* d_in, const int* in_sizes, int n_in,
                              void* d_out, int out_size, void* d_ws, size_t ws_size,
                              hipStream_t stream)
{
    const float* x    = (const float*)d_in[0];
    const float* We1  = (const float*)d_in[1];
    const float* be1  = (const float*)d_in[2];
    const float* We2  = (const float*)d_in[3];
    const float* be2  = (const float*)d_in[4];
    const float* Wih0 = (const float*)d_in[5];
    const float* Whh0 = (const float*)d_in[6];
    const float* bih0 = (const float*)d_in[7];
    const float* bhh0 = (const float*)d_in[8];
    const float* Wih1 = (const float*)d_in[9];
    const float* Whh1 = (const float*)d_in[10];
    const float* bih1 = (const float*)d_in[11];
    const float* bhh1 = (const float*)d_in[12];
    const float* Wc1  = (const float*)d_in[13];
    const float* bc1  = (const float*)d_in[14];
    const float* Wc2  = (const float*)d_in[15];
    const float* bc2  = (const float*)d_in[16];
    const float* Wd1  = (const float*)d_in[17];
    const float* bd1  = (const float*)d_in[18];
    const float* Wd2  = (const float*)d_in[19];
    const float* bd2  = (const float*)d_in[20];
    float* out = (float*)d_out;

    float* ws    = (float*)d_ws;
    float* emb   = ws;                       // 64*2048*16  = 2,097,152 f
    float* xg0   = emb + 2097152;            // 64*2048*64  = 8,388,608 f
    float* flow  = xg0 + 8388608;            // 64*2048*16  = 2,097,152 f

    k1_embed<<<dim3(512), dim3(256), 0, stream>>>(x, We1, be1, We2, be2,
                                                  Wih0, bih0, bhh0, emb, xg0);
    k2_scan<<<dim3(64), dim3(64), 0, stream>>>(xg0, Whh0, Wih1, Whh1, bih1, bhh1, flow);
    k34_cons_head<<<dim3(192), dim3(512), 0, stream>>>(emb, flow, Wc1, bc1, Wc2, bc2,
                                                       Wd1, bd1, Wd2, bd2, out);
}